// Round 1
// baseline (17.930 us; speedup 1.0000x reference)
//
#include <hip/hip_runtime.h>
#include <math.h>

// Problem constants (match reference)
constexpr int S = 128;
constexpr int B = 2;
constexpr int M = 1024;
constexpr int C = 80;
constexpr int P = S * S * B;        // 32768
constexpr int NPROB = S * S * C;    // 1310720
constexpr int NPROB4 = NPROB / 4;   // 327680
constexpr float LAMBDA_COORD = 5.0f;
constexpr float LAMBDA_NO_OBJ = 0.5f;

__device__ __forceinline__ float nn_sqrt(float x) {
    float s = sqrtf(x);
    return isnan(s) ? 0.0f : s;   // jnp.nan_to_num(sqrt(x))
}

__global__ void __launch_bounds__(256)
yolo_loss_kernel(const float* __restrict__ main_boxes,   // [M,4]
                 const float* __restrict__ pred_boxes,   // [P,4]
                 const float* __restrict__ conf,         // [P]
                 const float* __restrict__ gmp,          // [S*S*C]
                 const float* __restrict__ gpp,          // [S*S*C]
                 const int*   __restrict__ matched_main, // [P]
                 const float* __restrict__ matched_iou,  // [P]
                 float* __restrict__ out)
{
    const int tid = blockIdx.x * blockDim.x + threadIdx.x;
    const int nthreads = gridDim.x * blockDim.x;
    float acc = 0.0f;

    // ---- box loss over P predictions ----
    const float4* pb4 = reinterpret_cast<const float4*>(pred_boxes);
    const float4* mb4 = reinterpret_cast<const float4*>(main_boxes);
    for (int p = tid; p < P; p += nthreads) {
        float c  = conf[p];
        int   mm = matched_main[p];
        if (mm >= 0) {
            float4 pb = pb4[p];
            float4 mb = mb4[mm];
            float dx = mb.x - pb.x;
            float dy = mb.y - pb.y;
            float xy = dx * dx + dy * dy;
            float dw = nn_sqrt(mb.z) - nn_sqrt(pb.z);
            float dh = nn_sqrt(mb.w) - nn_sqrt(pb.w);
            float wh = dw * dw + dh * dh;
            float dc = matched_iou[p] - c;
            acc += LAMBDA_COORD * (xy + wh) + dc * dc;
        } else {
            acc += LAMBDA_NO_OBJ * c * c;
        }
    }

    // ---- prob loss over S*S*C, float4-vectorized ----
    const float4* g1 = reinterpret_cast<const float4*>(gmp);
    const float4* g2 = reinterpret_cast<const float4*>(gpp);
    for (int i = tid; i < NPROB4; i += nthreads) {
        float4 a = g1[i];
        float4 b = g2[i];
        float d0 = a.x - b.x, d1 = a.y - b.y, d2 = a.z - b.z, d3 = a.w - b.w;
        acc += d0 * d0 + d1 * d1 + d2 * d2 + d3 * d3;
    }

    // ---- wave (64-lane) shuffle reduction ----
    #pragma unroll
    for (int off = 32; off > 0; off >>= 1)
        acc += __shfl_down(acc, off, 64);

    // ---- block reduction (256 threads -> 4 waves) ----
    __shared__ float wave_sums[4];
    const int lane = threadIdx.x & 63;
    const int wid  = threadIdx.x >> 6;
    if (lane == 0) wave_sums[wid] = acc;
    __syncthreads();
    if (threadIdx.x == 0) {
        float s = wave_sums[0] + wave_sums[1] + wave_sums[2] + wave_sums[3];
        atomicAdd(out, s);
    }
}

extern "C" void kernel_launch(void* const* d_in, const int* in_sizes, int n_in,
                              void* d_out, int out_size, void* d_ws, size_t ws_size,
                              hipStream_t stream) {
    const float* main_boxes   = (const float*)d_in[0];
    const float* pred_boxes   = (const float*)d_in[1];
    const float* conf         = (const float*)d_in[2];
    const float* gmp          = (const float*)d_in[3];
    const float* gpp          = (const float*)d_in[4];
    const int*   matched_main = (const int*)d_in[5];
    const float* matched_iou  = (const float*)d_in[6];
    float* out = (float*)d_out;

    // Harness poisons d_out once (0xAA) and never re-poisons between replays:
    // zero it on-stream every call (graph-capture-safe).
    hipMemsetAsync(out, 0, sizeof(float), stream);

    const int block = 256;
    const int grid  = 512;   // 131072 threads; ~2.5 float4 iters each on prob loss
    yolo_loss_kernel<<<grid, block, 0, stream>>>(
        main_boxes, pred_boxes, conf, gmp, gpp, matched_main, matched_iou, out);
}